// Round 14
// baseline (302.481 us; speedup 1.0000x reference)
//
#include <hip/hip_runtime.h>
#include <cstddef>
#include <cstdint>

#define MROWS 16384          // B*N = 4*4096
#define NSEQ  4096
#define ASTR  296            // LDS activation row stride (shorts)
#define SELU_SCALE  1.0507009873554805f
#define SELU_ASCALE 1.7580993408473766f   // scale*alpha

typedef short bf16x8 __attribute__((ext_vector_type(8)));
typedef float f32x4  __attribute__((ext_vector_type(4)));

__device__ __forceinline__ float selu_f(float x) {
    return x > 0.f ? SELU_SCALE * x : SELU_ASCALE * (__expf(x) - 1.f);
}
__device__ __forceinline__ unsigned short f2bf(float x) {
    union { float f; unsigned int u; } v; v.f = x;
    unsigned int r = v.u + 0x7fffu + ((v.u >> 16) & 1u);
    return (unsigned short)(r >> 16);
}
__device__ __forceinline__ unsigned short t2bf(float x) {
    union { float f; unsigned int u; } v; v.f = x;
    return (unsigned short)(v.u >> 16);
}

// ---------------------------------------------------------------------------
// prep: fp32 W[K][N] -> bf16 fragment-blocked WTf[ntile][ks][lane][8]
// ---------------------------------------------------------------------------
struct PrepEnt { const float* W; unsigned short* WTf; int N, K, ntiles, KS, tileOff, tilesN; };
struct PrepArgs {
    PrepEnt e[16];
    const float *b21, *b22, *boid, *boch, *bdc1, *bin1;
    float *bc12, *boo, *bcat;
};
__global__ __launch_bounds__(256) void prep_kernel(PrepArgs pa) {
    if (blockIdx.y == 1) {
        if (blockIdx.x == 0) {
            int t = threadIdx.x;
            if (t < 32) pa.bc12[t] = pa.b21[t];
            else if (t < 64) pa.bc12[t] = pa.b22[t - 32];
            else if (t < 96) {
                int j = t - 64;
                pa.boo[j] = j < 8 ? pa.boid[j] : ((j >= 16 && j < 18) ? pa.boch[j - 16] : 0.f);
            }
        } else if (blockIdx.x == 1) {
            pa.bcat[threadIdx.x] = pa.bdc1[threadIdx.x];
        } else if (blockIdx.x == 2) {
            pa.bcat[256 + threadIdx.x] = pa.bin1[threadIdx.x];
        }
        return;
    }
    int bx = blockIdx.x;
    int ei = 0;
#pragma unroll
    for (int e = 1; e < 16; ++e)
        if (bx >= pa.e[e].tileOff) ei = e;
    PrepEnt E = pa.e[ei];
    int local = bx - E.tileOff;
    int tn = local / E.KS, tk = local - tn * E.KS;
    int k0 = tk * 32, n0 = tn * 32;

    __shared__ float ts[32][33];
    int t = threadIdx.x;
    {
        int kl = t >> 3, nl4 = (t & 7) * 4;
        int gk = k0 + kl;
#pragma unroll
        for (int j = 0; j < 4; ++j) {
            int gn = n0 + nl4 + j;
            float v = (gk < E.K && gn < E.N) ? E.W[(size_t)gk * E.N + gn] : 0.f;
            ts[nl4 + j][kl] = v;
        }
    }
    __syncthreads();
    int nl = t >> 3, kl4 = (t & 7) * 4;
    int n = n0 + nl;
    if (n < E.ntiles * 16) {
        ushort4 o;
        o.x = f2bf(ts[nl][kl4 + 0]);
        o.y = f2bf(ts[nl][kl4 + 1]);
        o.z = f2bf(ts[nl][kl4 + 2]);
        o.w = f2bf(ts[nl][kl4 + 3]);
        size_t dst = ((size_t)(n >> 4) * E.KS + tk) * 512 +
                     (size_t)((kl4 >> 3) * 16 + (n & 15)) * 8 + (kl4 & 7);
        *(ushort4*)(E.WTf + dst) = o;
    }
}

// ---------------------------------------------------------------------------
// building blocks (unchanged from R13)
// ---------------------------------------------------------------------------
template <int MT, int NT>
__device__ __forceinline__ void zero_acc(f32x4 (&acc)[MT][NT]) {
#pragma unroll
    for (int i = 0; i < MT; ++i)
#pragma unroll
        for (int nt = 0; nt < NT; ++nt) acc[i][nt] = (f32x4){0.f, 0.f, 0.f, 0.f};
}

template <int MT, int NT, int K>
__device__ __forceinline__ void compute_tiles(
    f32x4 (&acc)[MT][NT],
    const unsigned short* __restrict__ src, int sstr,
    const unsigned short* __restrict__ WTf,
    int col0, int ln)
{
    constexpr int KS = (K + 31) / 32;
    int quad = ln >> 4, l15 = ln & 15;
    const unsigned short* wp = WTf + (size_t)(col0 >> 4) * (KS * 512) + ln * 8;
    bf16x8 st[3][NT];
#pragma unroll
    for (int s = 0; s < 3; ++s) {
        if (s < KS) {
#pragma unroll
            for (int nt = 0; nt < NT; ++nt)
                st[s][nt] = *(const bf16x8*)(wp + nt * (KS * 512) + s * 512);
        }
    }
#pragma unroll
    for (int ks = 0; ks < KS; ++ks) {
        bf16x8 bnew[NT];
        if (ks + 3 < KS) {
#pragma unroll
            for (int nt = 0; nt < NT; ++nt)
                bnew[nt] = *(const bf16x8*)(wp + nt * (KS * 512) + (ks + 3) * 512);
        }
#pragma unroll
        for (int i = 0; i < MT; ++i) {
            bf16x8 af = *(const bf16x8*)(src + (i * 16 + l15) * sstr + ks * 32 + quad * 8);
#pragma unroll
            for (int nt = 0; nt < NT; ++nt)
                acc[i][nt] = __builtin_amdgcn_mfma_f32_16x16x32_bf16(af, st[ks % 3][nt], acc[i][nt], 0, 0, 0);
        }
        if (ks + 3 < KS) {
#pragma unroll
            for (int nt = 0; nt < NT; ++nt) st[ks % 3][nt] = bnew[nt];
        }
    }
}

template <int MT, int NT>
__device__ __forceinline__ void store_tiles(
    f32x4 (&acc)[MT][NT], unsigned short* __restrict__ dst,
    int col0, const float* __restrict__ bias, int Nreal, int act, int ln)
{
    int quad = ln >> 4, l15 = ln & 15;
#pragma unroll
    for (int nt = 0; nt < NT; ++nt) {
        int col = col0 + nt * 16 + l15;
        float bv = (bias && col < Nreal) ? bias[col] : 0.f;
#pragma unroll
        for (int i = 0; i < MT; ++i) {
#pragma unroll
            for (int r = 0; r < 4; ++r) {
                int row = i * 16 + quad * 4 + r;
                float v = acc[i][nt][r] + bv;
                if (act) v = selu_f(v);
                if (col >= Nreal) v = 0.f;
                dst[row * ASTR + col] = f2bf(v);
            }
        }
    }
}

// ---------------------------------------------------------------------------
// pre_mega: 512 blocks x 512 thr (8 waves, NT=2/wave); block = 32 rows.
// (unchanged from R13)
// ---------------------------------------------------------------------------
__global__ __launch_bounds__(512, 4) void pre_mega(
    const float* __restrict__ X,
    const unsigned short* __restrict__ WTdF, const float* __restrict__ bcat,
    const unsigned short* __restrict__ WTc12F, const float* __restrict__ bc12,
    const unsigned short* __restrict__ WTin2F, const float* __restrict__ b_in2,
    const unsigned short* __restrict__ WTin3F, const float* __restrict__ b_in3,
    const unsigned short* __restrict__ WTconvF,
    unsigned short* __restrict__ c1b, unsigned short* __restrict__ c2b,
    float* __restrict__ n1, float* __restrict__ n2,
    unsigned short* __restrict__ xwTb)
{
    __shared__ unsigned short encs[32 * 32];
    __shared__ unsigned short bufA[32 * ASTR];
    __shared__ unsigned short bufB[32 * ASTR];
    __shared__ float c12s[32 * 68];

    int tid = threadIdx.x, wv = tid >> 6, ln = tid & 63;
    int quad = ln >> 4, l15 = ln & 15;
    int row0 = blockIdx.x * 32;

#pragma unroll
    for (int p = 0; p < 2; ++p) {
        int idx = p * 512 + tid;
        int row = idx >> 5, col = idx & 31;
        float v = 0.f;
        if (col < 11) {
            int id = (int)X[(size_t)(row0 + row) * 15];
            v = (id == col) ? SELU_SCALE : 0.f;
        } else if (col < 25) {
            v = selu_f(X[(size_t)(row0 + row) * 15 + 1 + (col - 11)]);
        }
        encs[row * 32 + col] = f2bf(v);
    }
    __syncthreads();

#pragma unroll
    for (int ph = 0; ph < 2; ++ph) {
        f32x4 acc[2][2]; zero_acc<2, 2>(acc);
        compute_tiles<2, 2, 32>(acc, encs, 32, WTdF + (size_t)ph * 16 * 512, wv * 32, ln);
        store_tiles<2, 2>(acc, ph ? bufB : bufA, wv * 32, bcat + ph * 256, 256, 1, ln);
    }
    __syncthreads();

    f32x4 ax2[2][2]; zero_acc<2, 2>(ax2);
    compute_tiles<2, 2, 256>(ax2, bufB, ASTR, WTin2F, wv * 32, ln);
    f32x4 ac12[2][1];
    if (wv < 4) {
        zero_acc<2, 1>(ac12);
        compute_tiles<2, 1, 256>(ac12, bufA, ASTR, WTc12F, wv * 16, ln);
    }
    __syncthreads();
    store_tiles<2, 2>(ax2, bufA, wv * 32, b_in2, 256, 1, ln);
    if (wv < 4) {
        int col = wv * 16 + l15;
        float bv = bc12[col];
#pragma unroll
        for (int i = 0; i < 2; ++i)
#pragma unroll
            for (int r = 0; r < 4; ++r)
                c12s[(i * 16 + quad * 4 + r) * 68 + col] = ac12[i][0][r] + bv;
    }
    __syncthreads();

    if (tid < 32) {
        int grow = row0 + tid;
        const float* p = &c12s[tid * 68];
        float s1 = 0.f, s2 = 0.f;
        unsigned int o1[16], o2[16];
#pragma unroll
        for (int k = 0; k < 32; k += 2) {
            float a0 = p[k], a1 = p[k + 1];
            s1 += a0 * a0 + a1 * a1;
            o1[k >> 1] = (unsigned)f2bf(a0) | ((unsigned)f2bf(a1) << 16);
            float b0 = p[32 + k], b1 = p[33 + k];
            s2 += b0 * b0 + b1 * b1;
            o2[k >> 1] = (unsigned)f2bf(b0) | ((unsigned)f2bf(b1) << 16);
        }
        uint4* d1 = (uint4*)(c1b + (size_t)grow * 32);
        uint4* d2 = (uint4*)(c2b + (size_t)grow * 32);
#pragma unroll
        for (int j = 0; j < 4; ++j) {
            d1[j] = make_uint4(o1[4 * j], o1[4 * j + 1], o1[4 * j + 2], o1[4 * j + 3]);
            d2[j] = make_uint4(o2[4 * j], o2[4 * j + 1], o2[4 * j + 2], o2[4 * j + 3]);
        }
        n1[grow] = s1;
        n2[grow] = s2;
    }

    {
        f32x4 acc[2][2]; zero_acc<2, 2>(acc);
        compute_tiles<2, 2, 256>(acc, bufA, ASTR, WTin3F, wv * 32, ln);
        store_tiles<2, 2>(acc, bufB, wv * 32, b_in3, 256, 1, ln);
    }
    __syncthreads();
    {
        f32x4 acc[2][2]; zero_acc<2, 2>(acc);
        compute_tiles<2, 2, 256>(acc, bufB, ASTR, WTconvF, wv * 32, ln);
        store_tiles<2, 2>(acc, bufA, wv * 32, nullptr, 256, 0, ln);
    }
    __syncthreads();

    int b = row0 >> 12;
    int c0 = (row0 & 4095) >> 5;
    unsigned short* dst = xwTb + (size_t)(b * 128 + c0) * (256 * 32);
#pragma unroll
    for (int p = 0; p < 2; ++p) {
        int idx = p * 512 + tid;
        int h = idx >> 2, g = idx & 3;
        unsigned int w[4];
#pragma unroll
        for (int j = 0; j < 4; ++j) {
            unsigned int lo = bufA[(g * 8 + 2 * j) * ASTR + h];
            unsigned int hi = bufA[(g * 8 + 2 * j + 1) * ASTR + h];
            w[j] = lo | (hi << 16);
        }
        *(uint4*)(dst + (size_t)h * 32 + g * 8) = make_uint4(w[0], w[1], w[2], w[3]);
    }
}

// ---------------------------------------------------------------------------
// fused adjacency conv v7: 1024 blocks x 512 thr, tile 16i x 256h ->
// 4 out-of-phase blocks/CU (32 waves/CU) to fill latency stalls.
// Homogeneous R9 pipeline: per iter, B-frags chunk k + dot/exp chunk k+1 +
// main MFMAs chunk k; one barrier per 128-m chunk.
// ---------------------------------------------------------------------------
__global__ __launch_bounds__(512, 4) void adj_conv_mfma(
    const unsigned short* __restrict__ c1b, const unsigned short* __restrict__ c2b,
    const float* __restrict__ n1, const float* __restrict__ n2,
    const unsigned short* __restrict__ xwTb, const float* __restrict__ bconv,
    unsigned short* __restrict__ xc)
{
    __shared__ unsigned short wls[2][16][136];

    int tid = threadIdx.x, wv = tid >> 6, ln = tid & 63, quad = ln >> 4, l15 = ln & 15;
    int blk = blockIdx.x;
    int b = (blk >> 1) & 3;                      // XCD pair -> batch
    int iidx = ((blk >> 3) << 1) | (blk & 1);    // 0..255
    int i0 = iidx * 16;
    size_t base = (size_t)b * NSEQ;

    bf16x8 c1f = *(const bf16x8*)(c1b + (base + i0 + l15) * 32 + quad * 8);
    float4 n1v = *(const float4*)(n1 + base + i0 + quad * 4);

    const unsigned short* xwp0 = xwTb + (size_t)b * (128 * 256 * 32)
                               + ((size_t)(wv * 32 + l15) * 32 + quad * 8);
    const unsigned short* xwp1 = xwp0 + 8192;
    const unsigned short* xwp2 = xwp0 + 16384;
    const unsigned short* xwp3 = xwp0 + 24576;
    const unsigned short* c2p  = c2b + (base + wv * 16 + l15) * 32 + quad * 8;
    const float* n2p = n2 + base + wv * 16 + l15;

    f32x4 acc[2];
    acc[0] = (f32x4){0.f, 0.f, 0.f, 0.f};
    acc[1] = (f32x4){0.f, 0.f, 0.f, 0.f};

    // prologue: dot+exp chunk 0 -> wls[0]
    bf16x8 c2f = *(const bf16x8*)c2p;
    float nn2 = *n2p;
    c2p += 4096; n2p += 128;
    {
        f32x4 d0 = (f32x4){0.f, 0.f, 0.f, 0.f};
        d0 = __builtin_amdgcn_mfma_f32_16x16x32_bf16(c1f, c2f, d0, 0, 0, 0);
#pragma unroll
        for (int r = 0; r < 4; ++r) {
            float D0 = fmaf(-2.f, d0[r], n1v[r] + nn2);
            float t0 = __builtin_amdgcn_sqrtf(fmaxf(D0, 1e-12f));
            wls[0][quad * 4 + r][wv * 16 + l15] = t2bf(__expf(t0 * -4.f));
        }
    }
    c2f = *(const bf16x8*)c2p;
    nn2 = *n2p;
    c2p += 4096; n2p += 128;
    __syncthreads();

    for (int itr = 0; itr < 32; ++itr) {
        int p = itr & 1;
        // B-frags for chunk itr (L2; land during exp phase below)
        bf16x8 bfc[4][2];
#pragma unroll
        for (int ht = 0; ht < 2; ++ht) {
            bfc[0][ht] = *(const bf16x8*)(xwp0 + ht * 512);
            bfc[1][ht] = *(const bf16x8*)(xwp1 + ht * 512);
            bfc[2][ht] = *(const bf16x8*)(xwp2 + ht * 512);
            bfc[3][ht] = *(const bf16x8*)(xwp3 + ht * 512);
        }
        xwp0 += 32768; xwp1 += 32768; xwp2 += 32768; xwp3 += 32768;

        // dot+exp for chunk itr+1 -> wls[p^1]
        if (itr < 31) {
            f32x4 d0 = (f32x4){0.f, 0.f, 0.f, 0.f};
            d0 = __builtin_amdgcn_mfma_f32_16x16x32_bf16(c1f, c2f, d0, 0, 0, 0);
            bf16x8 c2n; float nnn;
            if (itr < 30) {
                c2n = *(const bf16x8*)c2p;
                nnn = *n2p;
                c2p += 4096; n2p += 128;
            }
#pragma unroll
            for (int r = 0; r < 4; ++r) {
                float D0 = fmaf(-2.f, d0[r], n1v[r] + nn2);
                float t0 = __builtin_amdgcn_sqrtf(fmaxf(D0, 1e-12f));
                wls[p ^ 1][quad * 4 + r][wv * 16 + l15] = t2bf(__expf(t0 * -4.f));
            }
            if (itr < 30) { c2f = c2n; nn2 = nnn; }
        }

        // main MFMAs for chunk itr
#pragma unroll
        for (int ks = 0; ks < 4; ++ks) {
            bf16x8 af = *(const bf16x8*)&wls[p][l15][ks * 32 + quad * 8];
            acc[0] = __builtin_amdgcn_mfma_f32_16x16x32_bf16(af, bfc[ks][0], acc[0], 0, 0, 0);
            acc[1] = __builtin_amdgcn_mfma_f32_16x16x32_bf16(af, bfc[ks][1], acc[1], 0, 0, 0);
        }
        __syncthreads();
    }

    // epilogue: + bconv, selu, store bf16 (stride 256)
#pragma unroll
    for (int ht = 0; ht < 2; ++ht) {
        int h = wv * 32 + ht * 16 + l15;
        float bv = bconv[h];
#pragma unroll
        for (int r = 0; r < 4; ++r) {
            int irow = i0 + quad * 4 + r;
            xc[(base + irow) * 256 + h] = f2bf(selu_f(acc[ht][r] + bv));
        }
    }
}

// ---------------------------------------------------------------------------
// post_mega: 512 blocks x 512 thr (8 waves, NT=2/wave); block = 32 rows.
// (unchanged from R13)
// ---------------------------------------------------------------------------
__global__ __launch_bounds__(512, 4) void post_mega(
    const float* __restrict__ X, const unsigned short* __restrict__ xc,
    const unsigned short* __restrict__ WTid1F, const float* __restrict__ b_id1,
    const unsigned short* __restrict__ WTid2F, const float* __restrict__ b_id2,
    const unsigned short* __restrict__ WTid3F, const float* __restrict__ b_id3,
    const unsigned short* __restrict__ WTooF, const float* __restrict__ boo,
    const unsigned short* __restrict__ WTm1F, const float* __restrict__ b_m1,
    const unsigned short* __restrict__ WTm2F, const float* __restrict__ b_m2,
    const unsigned short* __restrict__ WTm3F, const float* __restrict__ b_m3,
    const unsigned short* __restrict__ WTomF, const float* __restrict__ b_om,
    float* __restrict__ out)
{
    __shared__ unsigned short xcs[32 * ASTR];
    __shared__ unsigned short bufA[32 * ASTR];
    __shared__ unsigned short bufB[32 * ASTR];
    __shared__ float lgs[32 * 32];

    int tid = threadIdx.x, wv = tid >> 6, ln = tid & 63;
    int quad = ln >> 4, l15 = ln & 15;
    int row0 = blockIdx.x * 32;

#pragma unroll
    for (int p = 0; p < 2; ++p) {
        int idx = p * 512 + tid;
        int row = idx >> 5, c8 = (idx & 31) * 8;
        *(uint4*)&xcs[row * ASTR + c8] = *(const uint4*)(xc + (size_t)(row0 + row) * 256 + c8);
    }
#pragma unroll
    for (int p = 0; p < 3; ++p) {
        int idx = p * 512 + tid;
        if (idx < 1280) {
            int row = idx / 40, c = 256 + idx - row * 40;
            xcs[row * ASTR + c] = 0;
            bufB[row * ASTR + c] = 0;
        }
    }
    __syncthreads();

    {
        f32x4 acc[2][2]; zero_acc<2, 2>(acc);
        compute_tiles<2, 2, 256>(acc, xcs, ASTR, WTid1F, wv * 32, ln);
        store_tiles<2, 2>(acc, bufA, wv * 32, b_id1, 256, 1, ln);
    }
    __syncthreads();
    {
        f32x4 acc[2][2]; zero_acc<2, 2>(acc);
        compute_tiles<2, 2, 256>(acc, bufA, ASTR, WTid2F, wv * 32, ln);
        store_tiles<2, 2>(acc, bufB, wv * 32, b_id2, 256, 1, ln);
    }
    __syncthreads();
    {
        f32x4 acc[2][2]; zero_acc<2, 2>(acc);
        compute_tiles<2, 2, 256>(acc, bufB, ASTR, WTid3F, wv * 32, ln);
        store_tiles<2, 2>(acc, bufA, wv * 32, b_id3, 256, 1, ln);
    }
    __syncthreads();
    if (wv == 0) {
        f32x4 acc[2][2]; zero_acc<2, 2>(acc);
        compute_tiles<2, 2, 256>(acc, bufA, ASTR, WTooF, 0, ln);
#pragma unroll
        for (int nt = 0; nt < 2; ++nt) {
            int col = nt * 16 + l15;
            float bv = boo[col];
#pragma unroll
            for (int i = 0; i < 2; ++i)
#pragma unroll
                for (int r = 0; r < 4; ++r)
                    lgs[(i * 16 + quad * 4 + r) * 32 + col] = acc[i][nt][r] + bv;
        }
    }
    __syncthreads();
    if (tid < 32) {
        float* op = out + (size_t)(row0 + tid) * 13;
#pragma unroll
        for (int c = 0; c < 8; ++c) {
            float lg = lgs[tid * 32 + c];
            op[c] = lg;
            xcs[tid * ASTR + 256 + c] = f2bf(selu_f(lg));
        }
        op[11] = lgs[tid * 32 + 16];
        op[12] = lgs[tid * 32 + 17];
    }
    __syncthreads();
    {
        f32x4 acc[2][2]; zero_acc<2, 2>(acc);
        compute_tiles<2, 2, 288>(acc, xcs, ASTR, WTm1F, wv * 32, ln);
        store_tiles<2, 2>(acc, bufB, wv * 32, b_m1, 264, 1, ln);
        if (wv == 1) {
            f32x4 acx[2][1]; zero_acc<2, 1>(acx);
            compute_tiles<2, 1, 288>(acx, xcs, ASTR, WTm1F, 256, ln);
            store_tiles<2, 1>(acx, bufB, 256, b_m1, 264, 1, ln);
        }
    }
    __syncthreads();
    {
        f32x4 acc[2][2]; zero_acc<2, 2>(acc);
        compute_tiles<2, 2, 288>(acc, bufB, ASTR, WTm2F, wv * 32, ln);
        store_tiles<2, 2>(acc, bufA, wv * 32, b_m2, 256, 1, ln);
    }
    __syncthreads();
    {
        f32x4 acc[2][2]; zero_acc<2, 2>(acc);
        compute_tiles<2, 2, 256>(acc, bufA, ASTR, WTm3F, wv * 32, ln);
        store_tiles<2, 2>(acc, bufB, wv * 32, b_m3, 256, 1, ln);
    }
    __syncthreads();
    if (wv == 0) {
        f32x4 acc[2][1]; zero_acc<2, 1>(acc);
        compute_tiles<2, 1, 256>(acc, bufB, ASTR, WTomF, 0, ln);
        if (l15 < 3) {
            float bv = b_om[l15];
#pragma unroll
            for (int i = 0; i < 2; ++i)
#pragma unroll
                for (int r = 0; r < 4; ++r) {
                    int grow = row0 + i * 16 + quad * 4 + r;
                    out[(size_t)grow * 13 + 8 + l15] =
                        X[(size_t)grow * 15 + 2 + l15] + acc[i][0][r] + bv;
                }
        }
    }
}

extern "C" void kernel_launch(void* const* d_in, const int* in_sizes, int n_in,
                              void* d_out, int out_size, void* d_ws, size_t ws_size,
                              hipStream_t stream) {
    (void)in_sizes; (void)n_in; (void)out_size; (void)ws_size;

    const float* X = (const float*)d_in[0];
    const float* W_dc1 = (const float*)d_in[1];  const float* b_dc1 = (const float*)d_in[2];
    const float* W_dc21 = (const float*)d_in[3]; const float* b_dc21 = (const float*)d_in[4];
    const float* W_dc22 = (const float*)d_in[5]; const float* b_dc22 = (const float*)d_in[6];
    const float* W_in1 = (const float*)d_in[7];  const float* b_in1 = (const float*)d_in[8];
    const float* W_in2 = (const float*)d_in[9];  const float* b_in2 = (const float*)d_in[10];
    const float* W_in3 = (const float*)d_in[11]; const float* b_in3 = (const float*)d_in[12];
    const float* W_conv = (const float*)d_in[13]; const float* b_conv = (const float*)d_in[14];
    const float* W_id1 = (const float*)d_in[15]; const float* b_id1 = (const float*)d_in[16];
    const float* W_id2 = (const float*)d_in[17]; const float* b_id2 = (const float*)d_in[18];
    const float* W_id3 = (const float*)d_in[19]; const float* b_id3 = (const float*)d_in[20];
    const float* W_oid = (const float*)d_in[21]; const float* b_oid = (const float*)d_in[22];
    const float* W_och = (const float*)d_in[23]; const float* b_och = (const float*)d_in[24];
    const float* W_m1 = (const float*)d_in[25];  const float* b_m1 = (const float*)d_in[26];
    const float* W_m2 = (const float*)d_in[27];  const float* b_m2 = (const float*)d_in[28];
    const float* W_m3 = (const float*)d_in[29];  const float* b_m3 = (const float*)d_in[30];
    const float* W_om = (const float*)d_in[31];  const float* b_om = (const float*)d_in[32];

    const size_t M = MROWS;
    char* pw = (char*)d_ws;
    auto alloc = [&](size_t bytes) -> void* {
        void* r = (void*)pw;
        pw += (bytes + 255) & ~(size_t)255;
        return r;
    };
    unsigned short* c1b = (unsigned short*)alloc(M * 32 * 2);
    unsigned short* c2b = (unsigned short*)alloc(M * 32 * 2);
    float* n1 = (float*)alloc(M * 4);
    float* n2 = (float*)alloc(M * 4);
    unsigned short* xwTb = (unsigned short*)alloc((size_t)4 * 128 * 256 * 32 * 2);
    unsigned short* xcb = (unsigned short*)alloc(M * 256 * 2);
    unsigned short* WTdF   = (unsigned short*)alloc((size_t)2 * 16 * 1 * 512 * 2);
    unsigned short* WTc12F = (unsigned short*)alloc((size_t)4 * 8 * 512 * 2);
    unsigned short* WTin2F = (unsigned short*)alloc((size_t)16 * 8 * 512 * 2);
    unsigned short* WTin3F = (unsigned short*)alloc((size_t)16 * 8 * 512 * 2);
    unsigned short* WTconvF = (unsigned short*)alloc((size_t)16 * 8 * 512 * 2);
    unsigned short* WTid1F = (unsigned short*)alloc((size_t)16 * 8 * 512 * 2);
    unsigned short* WTid2F = (unsigned short*)alloc((size_t)16 * 8 * 512 * 2);
    unsigned short* WTid3F = (unsigned short*)alloc((size_t)16 * 8 * 512 * 2);
    unsigned short* WTm3F  = (unsigned short*)alloc((size_t)16 * 8 * 512 * 2);
    unsigned short* WTooF  = (unsigned short*)alloc((size_t)2 * 8 * 512 * 2);
    unsigned short* WTm1F  = (unsigned short*)alloc((size_t)17 * 9 * 512 * 2);
    unsigned short* WTm2F  = (unsigned short*)alloc((size_t)16 * 9 * 512 * 2);
    unsigned short* WTomF  = (unsigned short*)alloc((size_t)1 * 8 * 512 * 2);
    float* bc12 = (float*)alloc(64 * 4);
    float* boo = (float*)alloc(32 * 4);
    float* bcat = (float*)alloc(512 * 4);

    PrepArgs pa;
    int off = 0;
    auto ent = [&](const float* W, unsigned short* WTf, int N, int K, int ntiles) {
        PrepEnt e; e.W = W; e.WTf = WTf; e.N = N; e.K = K; e.ntiles = ntiles;
        e.KS = (K + 31) / 32;
        e.tilesN = (ntiles * 16 + 31) / 32;
        e.tileOff = off;
        off += e.tilesN * e.KS;
        return e;
    };
    pa.e[0]  = ent(W_dc1,  WTdF,                256, 25,  16);
    pa.e[1]  = ent(W_in1,  WTdF + 16 * 512,     256, 25,  16);
    pa.e[2]  = ent(W_dc21, WTc12F,              32,  256, 2);
    pa.e[3]  = ent(W_dc22, WTc12F + 2 * 8 * 512, 32, 256, 2);
    pa.e[4]  = ent(W_in2,  WTin2F,              256, 256, 16);
    pa.e[5]  = ent(W_in3,  WTin3F,              256, 256, 16);
    pa.e[6]  = ent(W_conv, WTconvF,             256, 256, 16);
    pa.e[7]  = ent(W_id1,  WTid1F,              256, 256, 16);
    pa.e[8]  = ent(W_id2,  WTid2F,              256, 256, 16);
    pa.e[9]  = ent(W_id3,  WTid3F,              256, 256, 16);
    pa.e[10] = ent(W_m3,   WTm3F,               256, 256, 16);
    pa.e[11] = ent(W_oid,  WTooF,               8,   256, 1);
    pa.e[12] = ent(W_och,  WTooF + 8 * 512,     2,   256, 1);
    pa.e[13] = ent(W_m1,   WTm1F,               264, 264, 17);
    pa.e[14] = ent(W_m2,   WTm2F,               256, 264, 16);
    pa.e[15] = ent(W_om,   WTomF,               3,   256, 1);
    pa.b21 = b_dc21; pa.b22 = b_dc22; pa.boid = b_oid; pa.boch = b_och;
    pa.bdc1 = b_dc1; pa.bin1 = b_in1;
    pa.bc12 = bc12; pa.boo = boo; pa.bcat = bcat;
    prep_kernel<<<dim3(off, 2), 256, 0, stream>>>(pa);

    pre_mega<<<dim3(512), 512, 0, stream>>>(X, WTdF, bcat, WTc12F, bc12,
                                            WTin2F, b_in2, WTin3F, b_in3, WTconvF,
                                            c1b, c2b, n1, n2, xwTb);

    adj_conv_mfma<<<dim3(1024), 512, 0, stream>>>(c1b, c2b, n1, n2, xwTb, b_conv, xcb);

    post_mega<<<dim3(512), 512, 0, stream>>>(X, xcb,
                                             WTid1F, b_id1, WTid2F, b_id2, WTid3F, b_id3,
                                             WTooF, boo, WTm1F, b_m1, WTm2F, b_m2,
                                             WTm3F, b_m3, WTomF, b_om, (float*)d_out);
}

// Round 15
// 241.450 us; speedup vs baseline: 1.2528x; 1.2528x over previous
//
#include <hip/hip_runtime.h>
#include <cstddef>
#include <cstdint>

#define MROWS 16384          // B*N = 4*4096
#define NSEQ  4096
#define ASTR  296            // LDS activation row stride (shorts)
#define SELU_SCALE  1.0507009873554805f
#define SELU_ASCALE 1.7580993408473766f   // scale*alpha

typedef short bf16x8 __attribute__((ext_vector_type(8)));
typedef float f32x4  __attribute__((ext_vector_type(4)));

__device__ __forceinline__ float selu_f(float x) {
    return x > 0.f ? SELU_SCALE * x : SELU_ASCALE * (__expf(x) - 1.f);
}
__device__ __forceinline__ unsigned short f2bf(float x) {
    union { float f; unsigned int u; } v; v.f = x;
    unsigned int r = v.u + 0x7fffu + ((v.u >> 16) & 1u);
    return (unsigned short)(r >> 16);
}
__device__ __forceinline__ unsigned short t2bf(float x) {
    union { float f; unsigned int u; } v; v.f = x;
    return (unsigned short)(v.u >> 16);
}

// ---------------------------------------------------------------------------
// prep: fp32 W[K][N] -> bf16 fragment-blocked WTf[ntile][ks][lane][8]
// ---------------------------------------------------------------------------
struct PrepEnt { const float* W; unsigned short* WTf; int N, K, ntiles, KS, tileOff, tilesN; };
struct PrepArgs {
    PrepEnt e[16];
    const float *b21, *b22, *boid, *boch, *bdc1, *bin1;
    float *bc12, *boo, *bcat;
};
__global__ __launch_bounds__(256) void prep_kernel(PrepArgs pa) {
    if (blockIdx.y == 1) {
        if (blockIdx.x == 0) {
            int t = threadIdx.x;
            if (t < 32) pa.bc12[t] = pa.b21[t];
            else if (t < 64) pa.bc12[t] = pa.b22[t - 32];
            else if (t < 96) {
                int j = t - 64;
                pa.boo[j] = j < 8 ? pa.boid[j] : ((j >= 16 && j < 18) ? pa.boch[j - 16] : 0.f);
            }
        } else if (blockIdx.x == 1) {
            pa.bcat[threadIdx.x] = pa.bdc1[threadIdx.x];
        } else if (blockIdx.x == 2) {
            pa.bcat[256 + threadIdx.x] = pa.bin1[threadIdx.x];
        }
        return;
    }
    int bx = blockIdx.x;
    int ei = 0;
#pragma unroll
    for (int e = 1; e < 16; ++e)
        if (bx >= pa.e[e].tileOff) ei = e;
    PrepEnt E = pa.e[ei];
    int local = bx - E.tileOff;
    int tn = local / E.KS, tk = local - tn * E.KS;
    int k0 = tk * 32, n0 = tn * 32;

    __shared__ float ts[32][33];
    int t = threadIdx.x;
    {
        int kl = t >> 3, nl4 = (t & 7) * 4;
        int gk = k0 + kl;
#pragma unroll
        for (int j = 0; j < 4; ++j) {
            int gn = n0 + nl4 + j;
            float v = (gk < E.K && gn < E.N) ? E.W[(size_t)gk * E.N + gn] : 0.f;
            ts[nl4 + j][kl] = v;
        }
    }
    __syncthreads();
    int nl = t >> 3, kl4 = (t & 7) * 4;
    int n = n0 + nl;
    if (n < E.ntiles * 16) {
        ushort4 o;
        o.x = f2bf(ts[nl][kl4 + 0]);
        o.y = f2bf(ts[nl][kl4 + 1]);
        o.z = f2bf(ts[nl][kl4 + 2]);
        o.w = f2bf(ts[nl][kl4 + 3]);
        size_t dst = ((size_t)(n >> 4) * E.KS + tk) * 512 +
                     (size_t)((kl4 >> 3) * 16 + (n & 15)) * 8 + (kl4 & 7);
        *(ushort4*)(E.WTf + dst) = o;
    }
}

// ---------------------------------------------------------------------------
// building blocks
// ---------------------------------------------------------------------------
template <int MT, int NT>
__device__ __forceinline__ void zero_acc(f32x4 (&acc)[MT][NT]) {
#pragma unroll
    for (int i = 0; i < MT; ++i)
#pragma unroll
        for (int nt = 0; nt < NT; ++nt) acc[i][nt] = (f32x4){0.f, 0.f, 0.f, 0.f};
}

template <int MT, int NT, int K>
__device__ __forceinline__ void compute_tiles(
    f32x4 (&acc)[MT][NT],
    const unsigned short* __restrict__ src, int sstr,
    const unsigned short* __restrict__ WTf,
    int col0, int ln)
{
    constexpr int KS = (K + 31) / 32;
    int quad = ln >> 4, l15 = ln & 15;
    const unsigned short* wp = WTf + (size_t)(col0 >> 4) * (KS * 512) + ln * 8;
    bf16x8 st[3][NT];
#pragma unroll
    for (int s = 0; s < 3; ++s) {
        if (s < KS) {
#pragma unroll
            for (int nt = 0; nt < NT; ++nt)
                st[s][nt] = *(const bf16x8*)(wp + nt * (KS * 512) + s * 512);
        }
    }
#pragma unroll
    for (int ks = 0; ks < KS; ++ks) {
        bf16x8 bnew[NT];
        if (ks + 3 < KS) {
#pragma unroll
            for (int nt = 0; nt < NT; ++nt)
                bnew[nt] = *(const bf16x8*)(wp + nt * (KS * 512) + (ks + 3) * 512);
        }
#pragma unroll
        for (int i = 0; i < MT; ++i) {
            bf16x8 af = *(const bf16x8*)(src + (i * 16 + l15) * sstr + ks * 32 + quad * 8);
#pragma unroll
            for (int nt = 0; nt < NT; ++nt)
                acc[i][nt] = __builtin_amdgcn_mfma_f32_16x16x32_bf16(af, st[ks % 3][nt], acc[i][nt], 0, 0, 0);
        }
        if (ks + 3 < KS) {
#pragma unroll
            for (int nt = 0; nt < NT; ++nt) st[ks % 3][nt] = bnew[nt];
        }
    }
}

template <int MT, int NT>
__device__ __forceinline__ void store_tiles(
    f32x4 (&acc)[MT][NT], unsigned short* __restrict__ dst,
    int col0, const float* __restrict__ bias, int Nreal, int act, int ln)
{
    int quad = ln >> 4, l15 = ln & 15;
#pragma unroll
    for (int nt = 0; nt < NT; ++nt) {
        int col = col0 + nt * 16 + l15;
        float bv = (bias && col < Nreal) ? bias[col] : 0.f;
#pragma unroll
        for (int i = 0; i < MT; ++i) {
#pragma unroll
            for (int r = 0; r < 4; ++r) {
                int row = i * 16 + quad * 4 + r;
                float v = acc[i][nt][r] + bv;
                if (act) v = selu_f(v);
                if (col >= Nreal) v = 0.f;
                dst[row * ASTR + col] = f2bf(v);
            }
        }
    }
}

// ---------------------------------------------------------------------------
// pre_mega: 512 blocks x 512 thr (8 waves, NT=2/wave); block = 32 rows.
// (512,6) -> 3 blocks/CU = 24 waves/CU (LDS 49KB x3 fits 160KB).
// ---------------------------------------------------------------------------
__global__ __launch_bounds__(512, 6) void pre_mega(
    const float* __restrict__ X,
    const unsigned short* __restrict__ WTdF, const float* __restrict__ bcat,
    const unsigned short* __restrict__ WTc12F, const float* __restrict__ bc12,
    const unsigned short* __restrict__ WTin2F, const float* __restrict__ b_in2,
    const unsigned short* __restrict__ WTin3F, const float* __restrict__ b_in3,
    const unsigned short* __restrict__ WTconvF,
    unsigned short* __restrict__ c1b, unsigned short* __restrict__ c2b,
    float* __restrict__ n1, float* __restrict__ n2,
    unsigned short* __restrict__ xwTb)
{
    __shared__ unsigned short encs[32 * 32];
    __shared__ unsigned short bufA[32 * ASTR];
    __shared__ unsigned short bufB[32 * ASTR];
    __shared__ float c12s[32 * 68];

    int tid = threadIdx.x, wv = tid >> 6, ln = tid & 63;
    int quad = ln >> 4, l15 = ln & 15;
    int row0 = blockIdx.x * 32;

#pragma unroll
    for (int p = 0; p < 2; ++p) {
        int idx = p * 512 + tid;
        int row = idx >> 5, col = idx & 31;
        float v = 0.f;
        if (col < 11) {
            int id = (int)X[(size_t)(row0 + row) * 15];
            v = (id == col) ? SELU_SCALE : 0.f;
        } else if (col < 25) {
            v = selu_f(X[(size_t)(row0 + row) * 15 + 1 + (col - 11)]);
        }
        encs[row * 32 + col] = f2bf(v);
    }
    __syncthreads();

#pragma unroll
    for (int ph = 0; ph < 2; ++ph) {
        f32x4 acc[2][2]; zero_acc<2, 2>(acc);
        compute_tiles<2, 2, 32>(acc, encs, 32, WTdF + (size_t)ph * 16 * 512, wv * 32, ln);
        store_tiles<2, 2>(acc, ph ? bufB : bufA, wv * 32, bcat + ph * 256, 256, 1, ln);
    }
    __syncthreads();

    f32x4 ax2[2][2]; zero_acc<2, 2>(ax2);
    compute_tiles<2, 2, 256>(ax2, bufB, ASTR, WTin2F, wv * 32, ln);
    f32x4 ac12[2][1];
    if (wv < 4) {
        zero_acc<2, 1>(ac12);
        compute_tiles<2, 1, 256>(ac12, bufA, ASTR, WTc12F, wv * 16, ln);
    }
    __syncthreads();
    store_tiles<2, 2>(ax2, bufA, wv * 32, b_in2, 256, 1, ln);
    if (wv < 4) {
        int col = wv * 16 + l15;
        float bv = bc12[col];
#pragma unroll
        for (int i = 0; i < 2; ++i)
#pragma unroll
            for (int r = 0; r < 4; ++r)
                c12s[(i * 16 + quad * 4 + r) * 68 + col] = ac12[i][0][r] + bv;
    }
    __syncthreads();

    if (tid < 32) {
        int grow = row0 + tid;
        const float* p = &c12s[tid * 68];
        float s1 = 0.f, s2 = 0.f;
        unsigned int o1[16], o2[16];
#pragma unroll
        for (int k = 0; k < 32; k += 2) {
            float a0 = p[k], a1 = p[k + 1];
            s1 += a0 * a0 + a1 * a1;
            o1[k >> 1] = (unsigned)f2bf(a0) | ((unsigned)f2bf(a1) << 16);
            float b0 = p[32 + k], b1 = p[33 + k];
            s2 += b0 * b0 + b1 * b1;
            o2[k >> 1] = (unsigned)f2bf(b0) | ((unsigned)f2bf(b1) << 16);
        }
        uint4* d1 = (uint4*)(c1b + (size_t)grow * 32);
        uint4* d2 = (uint4*)(c2b + (size_t)grow * 32);
#pragma unroll
        for (int j = 0; j < 4; ++j) {
            d1[j] = make_uint4(o1[4 * j], o1[4 * j + 1], o1[4 * j + 2], o1[4 * j + 3]);
            d2[j] = make_uint4(o2[4 * j], o2[4 * j + 1], o2[4 * j + 2], o2[4 * j + 3]);
        }
        n1[grow] = s1;
        n2[grow] = s2;
    }

    {
        f32x4 acc[2][2]; zero_acc<2, 2>(acc);
        compute_tiles<2, 2, 256>(acc, bufA, ASTR, WTin3F, wv * 32, ln);
        store_tiles<2, 2>(acc, bufB, wv * 32, b_in3, 256, 1, ln);
    }
    __syncthreads();
    {
        f32x4 acc[2][2]; zero_acc<2, 2>(acc);
        compute_tiles<2, 2, 256>(acc, bufB, ASTR, WTconvF, wv * 32, ln);
        store_tiles<2, 2>(acc, bufA, wv * 32, nullptr, 256, 0, ln);
    }
    __syncthreads();

    int b = row0 >> 12;
    int c0 = (row0 & 4095) >> 5;
    unsigned short* dst = xwTb + (size_t)(b * 128 + c0) * (256 * 32);
#pragma unroll
    for (int p = 0; p < 2; ++p) {
        int idx = p * 512 + tid;
        int h = idx >> 2, g = idx & 3;
        unsigned int w[4];
#pragma unroll
        for (int j = 0; j < 4; ++j) {
            unsigned int lo = bufA[(g * 8 + 2 * j) * ASTR + h];
            unsigned int hi = bufA[(g * 8 + 2 * j + 1) * ASTR + h];
            w[j] = lo | (hi << 16);
        }
        *(uint4*)(dst + (size_t)h * 32 + g * 8) = make_uint4(w[0], w[1], w[2], w[3]);
    }
}

// ---------------------------------------------------------------------------
// fused adjacency conv (R9/R11 homogeneous pipeline — best measured)
// 512 blocks x 512 thr, tile 32i x 256h, one barrier per 128-m chunk.
// ---------------------------------------------------------------------------
__global__ __launch_bounds__(512, 4) void adj_conv_mfma(
    const unsigned short* __restrict__ c1b, const unsigned short* __restrict__ c2b,
    const float* __restrict__ n1, const float* __restrict__ n2,
    const unsigned short* __restrict__ xwTb, const float* __restrict__ bconv,
    unsigned short* __restrict__ xc)
{
    __shared__ unsigned short wls[2][32][136];

    int tid = threadIdx.x, wv = tid >> 6, ln = tid & 63, quad = ln >> 4, l15 = ln & 15;
    int blk = blockIdx.x;
    int b = (blk >> 1) & 3;
    int iidx = ((blk >> 3) << 1) | (blk & 1);
    int i0 = iidx * 32;
    size_t base = (size_t)b * NSEQ;

    bf16x8 c1f0 = *(const bf16x8*)(c1b + (base + i0 + l15) * 32 + quad * 8);
    bf16x8 c1f1 = *(const bf16x8*)(c1b + (base + i0 + 16 + l15) * 32 + quad * 8);
    float4 n1v0 = *(const float4*)(n1 + base + i0 + quad * 4);
    float4 n1v1 = *(const float4*)(n1 + base + i0 + 16 + quad * 4);

    const unsigned short* xwp0 = xwTb + (size_t)b * (128 * 256 * 32)
                               + ((size_t)(wv * 32 + l15) * 32 + quad * 8);
    const unsigned short* xwp1 = xwp0 + 8192;
    const unsigned short* xwp2 = xwp0 + 16384;
    const unsigned short* xwp3 = xwp0 + 24576;
    const unsigned short* c2p  = c2b + (base + wv * 16 + l15) * 32 + quad * 8;
    const float* n2p = n2 + base + wv * 16 + l15;

    f32x4 acc[2][2];
#pragma unroll
    for (int i = 0; i < 2; ++i)
#pragma unroll
        for (int j = 0; j < 2; ++j) acc[i][j] = (f32x4){0.f, 0.f, 0.f, 0.f};

    bf16x8 c2f = *(const bf16x8*)c2p;
    float nn2 = *n2p;
    c2p += 4096; n2p += 128;
    {
        f32x4 d0 = (f32x4){0.f, 0.f, 0.f, 0.f};
        f32x4 d1 = (f32x4){0.f, 0.f, 0.f, 0.f};
        d0 = __builtin_amdgcn_mfma_f32_16x16x32_bf16(c1f0, c2f, d0, 0, 0, 0);
        d1 = __builtin_amdgcn_mfma_f32_16x16x32_bf16(c1f1, c2f, d1, 0, 0, 0);
#pragma unroll
        for (int r = 0; r < 4; ++r) {
            float D0 = fmaf(-2.f, d0[r], n1v0[r] + nn2);
            float D1 = fmaf(-2.f, d1[r], n1v1[r] + nn2);
            float t0 = __builtin_amdgcn_sqrtf(fmaxf(D0, 1e-12f));
            float t1 = __builtin_amdgcn_sqrtf(fmaxf(D1, 1e-12f));
            wls[0][quad * 4 + r][wv * 16 + l15]      = t2bf(__expf(t0 * -4.f));
            wls[0][16 + quad * 4 + r][wv * 16 + l15] = t2bf(__expf(t1 * -4.f));
        }
    }
    c2f = *(const bf16x8*)c2p;
    nn2 = *n2p;
    c2p += 4096; n2p += 128;
    __syncthreads();

    for (int itr = 0; itr < 32; ++itr) {
        int p = itr & 1;
        bf16x8 bfc[4][2];
#pragma unroll
        for (int ht = 0; ht < 2; ++ht) {
            bfc[0][ht] = *(const bf16x8*)(xwp0 + ht * 512);
            bfc[1][ht] = *(const bf16x8*)(xwp1 + ht * 512);
            bfc[2][ht] = *(const bf16x8*)(xwp2 + ht * 512);
            bfc[3][ht] = *(const bf16x8*)(xwp3 + ht * 512);
        }
        xwp0 += 32768; xwp1 += 32768; xwp2 += 32768; xwp3 += 32768;

        if (itr < 31) {
            f32x4 d0 = (f32x4){0.f, 0.f, 0.f, 0.f};
            f32x4 d1 = (f32x4){0.f, 0.f, 0.f, 0.f};
            d0 = __builtin_amdgcn_mfma_f32_16x16x32_bf16(c1f0, c2f, d0, 0, 0, 0);
            d1 = __builtin_amdgcn_mfma_f32_16x16x32_bf16(c1f1, c2f, d1, 0, 0, 0);
            bf16x8 c2n; float nnn;
            if (itr < 30) {
                c2n = *(const bf16x8*)c2p;
                nnn = *n2p;
                c2p += 4096; n2p += 128;
            }
#pragma unroll
            for (int r = 0; r < 4; ++r) {
                float D0 = fmaf(-2.f, d0[r], n1v0[r] + nn2);
                float D1 = fmaf(-2.f, d1[r], n1v1[r] + nn2);
                float t0 = __builtin_amdgcn_sqrtf(fmaxf(D0, 1e-12f));
                float t1 = __builtin_amdgcn_sqrtf(fmaxf(D1, 1e-12f));
                wls[p ^ 1][quad * 4 + r][wv * 16 + l15]      = t2bf(__expf(t0 * -4.f));
                wls[p ^ 1][16 + quad * 4 + r][wv * 16 + l15] = t2bf(__expf(t1 * -4.f));
            }
            if (itr < 30) { c2f = c2n; nn2 = nnn; }
        }

#pragma unroll
        for (int ks = 0; ks < 4; ++ks) {
            bf16x8 af0 = *(const bf16x8*)&wls[p][l15][ks * 32 + quad * 8];
            bf16x8 af1 = *(const bf16x8*)&wls[p][16 + l15][ks * 32 + quad * 8];
            acc[0][0] = __builtin_amdgcn_mfma_f32_16x16x32_bf16(af0, bfc[ks][0], acc[0][0], 0, 0, 0);
            acc[0][1] = __builtin_amdgcn_mfma_f32_16x16x32_bf16(af0, bfc[ks][1], acc[0][1], 0, 0, 0);
            acc[1][0] = __builtin_amdgcn_mfma_f32_16x16x32_bf16(af1, bfc[ks][0], acc[1][0], 0, 0, 0);
            acc[1][1] = __builtin_amdgcn_mfma_f32_16x16x32_bf16(af1, bfc[ks][1], acc[1][1], 0, 0, 0);
        }
        __syncthreads();
    }

#pragma unroll
    for (int mi = 0; mi < 2; ++mi) {
#pragma unroll
        for (int ht = 0; ht < 2; ++ht) {
            int h = wv * 32 + ht * 16 + l15;
            float bv = bconv[h];
#pragma unroll
            for (int r = 0; r < 4; ++r) {
                int irow = i0 + mi * 16 + quad * 4 + r;
                xc[(base + irow) * 256 + h] = f2bf(selu_f(acc[mi][ht][r] + bv));
            }
        }
    }
}

// ---------------------------------------------------------------------------
// post_mega: 512 blocks x 512 thr (8 waves, NT=2/wave); block = 32 rows.
// ---------------------------------------------------------------------------
__global__ __launch_bounds__(512, 4) void post_mega(
    const float* __restrict__ X, const unsigned short* __restrict__ xc,
    const unsigned short* __restrict__ WTid1F, const float* __restrict__ b_id1,
    const unsigned short* __restrict__ WTid2F, const float* __restrict__ b_id2,
    const unsigned short* __restrict__ WTid3F, const float* __restrict__ b_id3,
    const unsigned short* __restrict__ WTooF, const float* __restrict__ boo,
    const unsigned short* __restrict__ WTm1F, const float* __restrict__ b_m1,
    const unsigned short* __restrict__ WTm2F, const float* __restrict__ b_m2,
    const unsigned short* __restrict__ WTm3F, const float* __restrict__ b_m3,
    const unsigned short* __restrict__ WTomF, const float* __restrict__ b_om,
    float* __restrict__ out)
{
    __shared__ unsigned short xcs[32 * ASTR];
    __shared__ unsigned short bufA[32 * ASTR];
    __shared__ unsigned short bufB[32 * ASTR];
    __shared__ float lgs[32 * 32];

    int tid = threadIdx.x, wv = tid >> 6, ln = tid & 63;
    int quad = ln >> 4, l15 = ln & 15;
    int row0 = blockIdx.x * 32;

#pragma unroll
    for (int p = 0; p < 2; ++p) {
        int idx = p * 512 + tid;
        int row = idx >> 5, c8 = (idx & 31) * 8;
        *(uint4*)&xcs[row * ASTR + c8] = *(const uint4*)(xc + (size_t)(row0 + row) * 256 + c8);
    }
#pragma unroll
    for (int p = 0; p < 3; ++p) {
        int idx = p * 512 + tid;
        if (idx < 1280) {
            int row = idx / 40, c = 256 + idx - row * 40;
            xcs[row * ASTR + c] = 0;
            bufB[row * ASTR + c] = 0;
        }
    }
    __syncthreads();

    {
        f32x4 acc[2][2]; zero_acc<2, 2>(acc);
        compute_tiles<2, 2, 256>(acc, xcs, ASTR, WTid1F, wv * 32, ln);
        store_tiles<2, 2>(acc, bufA, wv * 32, b_id1, 256, 1, ln);
    }
    __syncthreads();
    {
        f32x4 acc[2][2]; zero_acc<2, 2>(acc);
        compute_tiles<2, 2, 256>(acc, bufA, ASTR, WTid2F, wv * 32, ln);
        store_tiles<2, 2>(acc, bufB, wv * 32, b_id2, 256, 1, ln);
    }
    __syncthreads();
    {
        f32x4 acc[2][2]; zero_acc<2, 2>(acc);
        compute_tiles<2, 2, 256>(acc, bufB, ASTR, WTid3F, wv * 32, ln);
        store_tiles<2, 2>(acc, bufA, wv * 32, b_id3, 256, 1, ln);
    }
    __syncthreads();
    if (wv == 0) {
        f32x4 acc[2][2]; zero_acc<2, 2>(acc);
        compute_tiles<2, 2, 256>(acc, bufA, ASTR, WTooF, 0, ln);
#pragma unroll
        for (int nt = 0; nt < 2; ++nt) {
            int col = nt * 16 + l15;
            float bv = boo[col];
#pragma unroll
            for (int i = 0; i < 2; ++i)
#pragma unroll
                for (int r = 0; r < 4; ++r)
                    lgs[(i * 16 + quad * 4 + r) * 32 + col] = acc[i][nt][r] + bv;
        }
    }
    __syncthreads();
    if (tid < 32) {
        float* op = out + (size_t)(row0 + tid) * 13;
#pragma unroll
        for (int c = 0; c < 8; ++c) {
            float lg = lgs[tid * 32 + c];
            op[c] = lg;
            xcs[tid * ASTR + 256 + c] = f2bf(selu_f(lg));
        }
        op[11] = lgs[tid * 32 + 16];
        op[12] = lgs[tid * 32 + 17];
    }
    __syncthreads();
    {
        f32x4 acc[2][2]; zero_acc<2, 2>(acc);
        compute_tiles<2, 2, 288>(acc, xcs, ASTR, WTm1F, wv * 32, ln);
        store_tiles<2, 2>(acc, bufB, wv * 32, b_m1, 264, 1, ln);
        if (wv == 1) {
            f32x4 acx[2][1]; zero_acc<2, 1>(acx);
            compute_tiles<2, 1, 288>(acx, xcs, ASTR, WTm1F, 256, ln);
            store_tiles<2, 1>(acx, bufB, 256, b_m1, 264, 1, ln);
        }
    }
    __syncthreads();
    {
        f32x4 acc[2][2]; zero_acc<2, 2>(acc);
        compute_tiles<2, 2, 288>(acc, bufB, ASTR, WTm2F, wv * 32, ln);
        store_tiles<2, 2>(acc, bufA, wv * 32, b_m2, 256, 1, ln);
    }
    __syncthreads();
    {
        f32x4 acc[2][2]; zero_acc<2, 2>(acc);
        compute_tiles<2, 2, 256>(acc, bufA, ASTR, WTm3F, wv * 32, ln);
        store_tiles<2, 2>(acc, bufB, wv * 32, b_m3, 256, 1, ln);
    }
    __syncthreads();
    if (wv == 0) {
        f32x4 acc[2][1]; zero_acc<2, 1>(acc);
        compute_tiles<2, 1, 256>(acc, bufB, ASTR, WTomF, 0, ln);
        if (l15 < 3) {
            float bv = b_om[l15];
#pragma unroll
            for (int i = 0; i < 2; ++i)
#pragma unroll
                for (int r = 0; r < 4; ++r) {
                    int grow = row0 + i * 16 + quad * 4 + r;
                    out[(size_t)grow * 13 + 8 + l15] =
                        X[(size_t)grow * 15 + 2 + l15] + acc[i][0][r] + bv;
                }
        }
    }
}

extern "C" void kernel_launch(void* const* d_in, const int* in_sizes, int n_in,
                              void* d_out, int out_size, void* d_ws, size_t ws_size,
                              hipStream_t stream) {
    (void)in_sizes; (void)n_in; (void)out_size; (void)ws_size;

    const float* X = (const float*)d_in[0];
    const float* W_dc1 = (const float*)d_in[1];  const float* b_dc1 = (const float*)d_in[2];
    const float* W_dc21 = (const float*)d_in[3]; const float* b_dc21 = (const float*)d_in[4];
    const float* W_dc22 = (const float*)d_in[5]; const float* b_dc22 = (const float*)d_in[6];
    const float* W_in1 = (const float*)d_in[7];  const float* b_in1 = (const float*)d_in[8];
    const float* W_in2 = (const float*)d_in[9];  const float* b_in2 = (const float*)d_in[10];
    const float* W_in3 = (const float*)d_in[11]; const float* b_in3 = (const float*)d_in[12];
    const float* W_conv = (const float*)d_in[13]; const float* b_conv = (const float*)d_in[14];
    const float* W_id1 = (const float*)d_in[15]; const float* b_id1 = (const float*)d_in[16];
    const float* W_id2 = (const float*)d_in[17]; const float* b_id2 = (const float*)d_in[18];
    const float* W_id3 = (const float*)d_in[19]; const float* b_id3 = (const float*)d_in[20];
    const float* W_oid = (const float*)d_in[21]; const float* b_oid = (const float*)d_in[22];
    const float* W_och = (const float*)d_in[23]; const float* b_och = (const float*)d_in[24];
    const float* W_m1 = (const float*)d_in[25];  const float* b_m1 = (const float*)d_in[26];
    const float* W_m2 = (const float*)d_in[27];  const float* b_m2 = (const float*)d_in[28];
    const float* W_m3 = (const float*)d_in[29];  const float* b_m3 = (const float*)d_in[30];
    const float* W_om = (const float*)d_in[31];  const float* b_om = (const float*)d_in[32];

    const size_t M = MROWS;
    char* pw = (char*)d_ws;
    auto alloc = [&](size_t bytes) -> void* {
        void* r = (void*)pw;
        pw += (bytes + 255) & ~(size_t)255;
        return r;
    };
    unsigned short* c1b = (unsigned short*)alloc(M * 32 * 2);
    unsigned short* c2b = (unsigned short*)alloc(M * 32 * 2);
    float* n1 = (float*)alloc(M * 4);
    float* n2 = (float*)alloc(M * 4);
    unsigned short* xwTb = (unsigned short*)alloc((size_t)4 * 128 * 256 * 32 * 2);
    unsigned short* xcb = (unsigned short*)alloc(M * 256 * 2);
    unsigned short* WTdF   = (unsigned short*)alloc((size_t)2 * 16 * 1 * 512 * 2);
    unsigned short* WTc12F = (unsigned short*)alloc((size_t)4 * 8 * 512 * 2);
    unsigned short* WTin2F = (unsigned short*)alloc((size_t)16 * 8 * 512 * 2);
    unsigned short* WTin3F = (unsigned short*)alloc((size_t)16 * 8 * 512 * 2);
    unsigned short* WTconvF = (unsigned short*)alloc((size_t)16 * 8 * 512 * 2);
    unsigned short* WTid1F = (unsigned short*)alloc((size_t)16 * 8 * 512 * 2);
    unsigned short* WTid2F = (unsigned short*)alloc((size_t)16 * 8 * 512 * 2);
    unsigned short* WTid3F = (unsigned short*)alloc((size_t)16 * 8 * 512 * 2);
    unsigned short* WTm3F  = (unsigned short*)alloc((size_t)16 * 8 * 512 * 2);
    unsigned short* WTooF  = (unsigned short*)alloc((size_t)2 * 8 * 512 * 2);
    unsigned short* WTm1F  = (unsigned short*)alloc((size_t)17 * 9 * 512 * 2);
    unsigned short* WTm2F  = (unsigned short*)alloc((size_t)16 * 9 * 512 * 2);
    unsigned short* WTomF  = (unsigned short*)alloc((size_t)1 * 8 * 512 * 2);
    float* bc12 = (float*)alloc(64 * 4);
    float* boo = (float*)alloc(32 * 4);
    float* bcat = (float*)alloc(512 * 4);

    PrepArgs pa;
    int off = 0;
    auto ent = [&](const float* W, unsigned short* WTf, int N, int K, int ntiles) {
        PrepEnt e; e.W = W; e.WTf = WTf; e.N = N; e.K = K; e.ntiles = ntiles;
        e.KS = (K + 31) / 32;
        e.tilesN = (ntiles * 16 + 31) / 32;
        e.tileOff = off;
        off += e.tilesN * e.KS;
        return e;
    };
    pa.e[0]  = ent(W_dc1,  WTdF,                256, 25,  16);
    pa.e[1]  = ent(W_in1,  WTdF + 16 * 512,     256, 25,  16);
    pa.e[2]  = ent(W_dc21, WTc12F,              32,  256, 2);
    pa.e[3]  = ent(W_dc22, WTc12F + 2 * 8 * 512, 32, 256, 2);
    pa.e[4]  = ent(W_in2,  WTin2F,              256, 256, 16);
    pa.e[5]  = ent(W_in3,  WTin3F,              256, 256, 16);
    pa.e[6]  = ent(W_conv, WTconvF,             256, 256, 16);
    pa.e[7]  = ent(W_id1,  WTid1F,              256, 256, 16);
    pa.e[8]  = ent(W_id2,  WTid2F,              256, 256, 16);
    pa.e[9]  = ent(W_id3,  WTid3F,              256, 256, 16);
    pa.e[10] = ent(W_m3,   WTm3F,               256, 256, 16);
    pa.e[11] = ent(W_oid,  WTooF,               8,   256, 1);
    pa.e[12] = ent(W_och,  WTooF + 8 * 512,     2,   256, 1);
    pa.e[13] = ent(W_m1,   WTm1F,               264, 264, 17);
    pa.e[14] = ent(W_m2,   WTm2F,               256, 264, 16);
    pa.e[15] = ent(W_om,   WTomF,               3,   256, 1);
    pa.b21 = b_dc21; pa.b22 = b_dc22; pa.boid = b_oid; pa.boch = b_och;
    pa.bdc1 = b_dc1; pa.bin1 = b_in1;
    pa.bc12 = bc12; pa.boo = boo; pa.bcat = bcat;
    prep_kernel<<<dim3(off, 2), 256, 0, stream>>>(pa);

    pre_mega<<<dim3(512), 512, 0, stream>>>(X, WTdF, bcat, WTc12F, bc12,
                                            WTin2F, b_in2, WTin3F, b_in3, WTconvF,
                                            c1b, c2b, n1, n2, xwTb);

    adj_conv_mfma<<<dim3(512), 512, 0, stream>>>(c1b, c2b, n1, n2, xwTb, b_conv, xcb);

    post_mega<<<dim3(512), 512, 0, stream>>>(X, xcb,
                                             WTid1F, b_id1, WTid2F, b_id2, WTid3F, b_id3,
                                             WTooF, boo, WTm1F, b_m1, WTm2F, b_m2,
                                             WTm3F, b_m3, WTomF, b_om, (float*)d_out);
}

// Round 16
// 234.421 us; speedup vs baseline: 1.2903x; 1.0300x over previous
//
#include <hip/hip_runtime.h>
#include <cstddef>
#include <cstdint>

#define MROWS 16384          // B*N = 4*4096
#define NSEQ  4096
#define ASTR  296            // LDS activation row stride (shorts)
#define SELU_SCALE  1.0507009873554805f
#define SELU_ASCALE 1.7580993408473766f   // scale*alpha

typedef short bf16x8 __attribute__((ext_vector_type(8)));
typedef float f32x4  __attribute__((ext_vector_type(4)));

__device__ __forceinline__ float selu_f(float x) {
    return x > 0.f ? SELU_SCALE * x : SELU_ASCALE * (__expf(x) - 1.f);
}
__device__ __forceinline__ unsigned short f2bf(float x) {
    union { float f; unsigned int u; } v; v.f = x;
    unsigned int r = v.u + 0x7fffu + ((v.u >> 16) & 1u);
    return (unsigned short)(r >> 16);
}
__device__ __forceinline__ unsigned short t2bf(float x) {
    union { float f; unsigned int u; } v; v.f = x;
    return (unsigned short)(v.u >> 16);
}

// ---------------------------------------------------------------------------
// prep: fp32 W[K][N] -> bf16 fragment-blocked WTf[ntile][ks][lane][8]
// ---------------------------------------------------------------------------
struct PrepEnt { const float* W; unsigned short* WTf; int N, K, ntiles, KS, tileOff, tilesN; };
struct PrepArgs {
    PrepEnt e[16];
    const float *b21, *b22, *boid, *boch, *bdc1, *bin1;
    float *bc12, *boo, *bcat;
};
__global__ __launch_bounds__(256) void prep_kernel(PrepArgs pa) {
    if (blockIdx.y == 1) {
        if (blockIdx.x == 0) {
            int t = threadIdx.x;
            if (t < 32) pa.bc12[t] = pa.b21[t];
            else if (t < 64) pa.bc12[t] = pa.b22[t - 32];
            else if (t < 96) {
                int j = t - 64;
                pa.boo[j] = j < 8 ? pa.boid[j] : ((j >= 16 && j < 18) ? pa.boch[j - 16] : 0.f);
            }
        } else if (blockIdx.x == 1) {
            pa.bcat[threadIdx.x] = pa.bdc1[threadIdx.x];
        } else if (blockIdx.x == 2) {
            pa.bcat[256 + threadIdx.x] = pa.bin1[threadIdx.x];
        }
        return;
    }
    int bx = blockIdx.x;
    int ei = 0;
#pragma unroll
    for (int e = 1; e < 16; ++e)
        if (bx >= pa.e[e].tileOff) ei = e;
    PrepEnt E = pa.e[ei];
    int local = bx - E.tileOff;
    int tn = local / E.KS, tk = local - tn * E.KS;
    int k0 = tk * 32, n0 = tn * 32;

    __shared__ float ts[32][33];
    int t = threadIdx.x;
    {
        int kl = t >> 3, nl4 = (t & 7) * 4;
        int gk = k0 + kl;
#pragma unroll
        for (int j = 0; j < 4; ++j) {
            int gn = n0 + nl4 + j;
            float v = (gk < E.K && gn < E.N) ? E.W[(size_t)gk * E.N + gn] : 0.f;
            ts[nl4 + j][kl] = v;
        }
    }
    __syncthreads();
    int nl = t >> 3, kl4 = (t & 7) * 4;
    int n = n0 + nl;
    if (n < E.ntiles * 16) {
        ushort4 o;
        o.x = f2bf(ts[nl][kl4 + 0]);
        o.y = f2bf(ts[nl][kl4 + 1]);
        o.z = f2bf(ts[nl][kl4 + 2]);
        o.w = f2bf(ts[nl][kl4 + 3]);
        size_t dst = ((size_t)(n >> 4) * E.KS + tk) * 512 +
                     (size_t)((kl4 >> 3) * 16 + (n & 15)) * 8 + (kl4 & 7);
        *(ushort4*)(E.WTf + dst) = o;
    }
}

// ---------------------------------------------------------------------------
// building blocks
// ---------------------------------------------------------------------------
template <int MT, int NT>
__device__ __forceinline__ void zero_acc(f32x4 (&acc)[MT][NT]) {
#pragma unroll
    for (int i = 0; i < MT; ++i)
#pragma unroll
        for (int nt = 0; nt < NT; ++nt) acc[i][nt] = (f32x4){0.f, 0.f, 0.f, 0.f};
}

template <int MT, int NT, int K>
__device__ __forceinline__ void compute_tiles(
    f32x4 (&acc)[MT][NT],
    const unsigned short* __restrict__ src, int sstr,
    const unsigned short* __restrict__ WTf,
    int col0, int ln)
{
    constexpr int KS = (K + 31) / 32;
    int quad = ln >> 4, l15 = ln & 15;
    const unsigned short* wp = WTf + (size_t)(col0 >> 4) * (KS * 512) + ln * 8;
    bf16x8 st[3][NT];
#pragma unroll
    for (int s = 0; s < 3; ++s) {
        if (s < KS) {
#pragma unroll
            for (int nt = 0; nt < NT; ++nt)
                st[s][nt] = *(const bf16x8*)(wp + nt * (KS * 512) + s * 512);
        }
    }
#pragma unroll
    for (int ks = 0; ks < KS; ++ks) {
        bf16x8 bnew[NT];
        if (ks + 3 < KS) {
#pragma unroll
            for (int nt = 0; nt < NT; ++nt)
                bnew[nt] = *(const bf16x8*)(wp + nt * (KS * 512) + (ks + 3) * 512);
        }
#pragma unroll
        for (int i = 0; i < MT; ++i) {
            bf16x8 af = *(const bf16x8*)(src + (i * 16 + l15) * sstr + ks * 32 + quad * 8);
#pragma unroll
            for (int nt = 0; nt < NT; ++nt)
                acc[i][nt] = __builtin_amdgcn_mfma_f32_16x16x32_bf16(af, st[ks % 3][nt], acc[i][nt], 0, 0, 0);
        }
        if (ks + 3 < KS) {
#pragma unroll
            for (int nt = 0; nt < NT; ++nt) st[ks % 3][nt] = bnew[nt];
        }
    }
}

template <int MT, int NT>
__device__ __forceinline__ void store_tiles(
    f32x4 (&acc)[MT][NT], unsigned short* __restrict__ dst,
    int col0, const float* __restrict__ bias, int Nreal, int act, int ln)
{
    int quad = ln >> 4, l15 = ln & 15;
#pragma unroll
    for (int nt = 0; nt < NT; ++nt) {
        int col = col0 + nt * 16 + l15;
        float bv = (bias && col < Nreal) ? bias[col] : 0.f;
#pragma unroll
        for (int i = 0; i < MT; ++i) {
#pragma unroll
            for (int r = 0; r < 4; ++r) {
                int row = i * 16 + quad * 4 + r;
                float v = acc[i][nt][r] + bv;
                if (act) v = selu_f(v);
                if (col >= Nreal) v = 0.f;
                dst[row * ASTR + col] = f2bf(v);
            }
        }
    }
}

// ---------------------------------------------------------------------------
// pre_mega: 512 blocks x 512 thr (8 waves, NT=2/wave); block = 32 rows.
// (512,6) -> 3 blocks/CU (R15 best).
// ---------------------------------------------------------------------------
__global__ __launch_bounds__(512, 6) void pre_mega(
    const float* __restrict__ X,
    const unsigned short* __restrict__ WTdF, const float* __restrict__ bcat,
    const unsigned short* __restrict__ WTc12F, const float* __restrict__ bc12,
    const unsigned short* __restrict__ WTin2F, const float* __restrict__ b_in2,
    const unsigned short* __restrict__ WTin3F, const float* __restrict__ b_in3,
    const unsigned short* __restrict__ WTconvF,
    unsigned short* __restrict__ c1b, unsigned short* __restrict__ c2b,
    float* __restrict__ n1, float* __restrict__ n2,
    unsigned short* __restrict__ xwTb)
{
    __shared__ unsigned short encs[32 * 32];
    __shared__ unsigned short bufA[32 * ASTR];
    __shared__ unsigned short bufB[32 * ASTR];
    __shared__ float c12s[32 * 68];

    int tid = threadIdx.x, wv = tid >> 6, ln = tid & 63;
    int quad = ln >> 4, l15 = ln & 15;
    int row0 = blockIdx.x * 32;

#pragma unroll
    for (int p = 0; p < 2; ++p) {
        int idx = p * 512 + tid;
        int row = idx >> 5, col = idx & 31;
        float v = 0.f;
        if (col < 11) {
            int id = (int)X[(size_t)(row0 + row) * 15];
            v = (id == col) ? SELU_SCALE : 0.f;
        } else if (col < 25) {
            v = selu_f(X[(size_t)(row0 + row) * 15 + 1 + (col - 11)]);
        }
        encs[row * 32 + col] = f2bf(v);
    }
    __syncthreads();

#pragma unroll
    for (int ph = 0; ph < 2; ++ph) {
        f32x4 acc[2][2]; zero_acc<2, 2>(acc);
        compute_tiles<2, 2, 32>(acc, encs, 32, WTdF + (size_t)ph * 16 * 512, wv * 32, ln);
        store_tiles<2, 2>(acc, ph ? bufB : bufA, wv * 32, bcat + ph * 256, 256, 1, ln);
    }
    __syncthreads();

    f32x4 ax2[2][2]; zero_acc<2, 2>(ax2);
    compute_tiles<2, 2, 256>(ax2, bufB, ASTR, WTin2F, wv * 32, ln);
    f32x4 ac12[2][1];
    if (wv < 4) {
        zero_acc<2, 1>(ac12);
        compute_tiles<2, 1, 256>(ac12, bufA, ASTR, WTc12F, wv * 16, ln);
    }
    __syncthreads();
    store_tiles<2, 2>(ax2, bufA, wv * 32, b_in2, 256, 1, ln);
    if (wv < 4) {
        int col = wv * 16 + l15;
        float bv = bc12[col];
#pragma unroll
        for (int i = 0; i < 2; ++i)
#pragma unroll
            for (int r = 0; r < 4; ++r)
                c12s[(i * 16 + quad * 4 + r) * 68 + col] = ac12[i][0][r] + bv;
    }
    __syncthreads();

    if (tid < 32) {
        int grow = row0 + tid;
        const float* p = &c12s[tid * 68];
        float s1 = 0.f, s2 = 0.f;
        unsigned int o1[16], o2[16];
#pragma unroll
        for (int k = 0; k < 32; k += 2) {
            float a0 = p[k], a1 = p[k + 1];
            s1 += a0 * a0 + a1 * a1;
            o1[k >> 1] = (unsigned)f2bf(a0) | ((unsigned)f2bf(a1) << 16);
            float b0 = p[32 + k], b1 = p[33 + k];
            s2 += b0 * b0 + b1 * b1;
            o2[k >> 1] = (unsigned)f2bf(b0) | ((unsigned)f2bf(b1) << 16);
        }
        uint4* d1 = (uint4*)(c1b + (size_t)grow * 32);
        uint4* d2 = (uint4*)(c2b + (size_t)grow * 32);
#pragma unroll
        for (int j = 0; j < 4; ++j) {
            d1[j] = make_uint4(o1[4 * j], o1[4 * j + 1], o1[4 * j + 2], o1[4 * j + 3]);
            d2[j] = make_uint4(o2[4 * j], o2[4 * j + 1], o2[4 * j + 2], o2[4 * j + 3]);
        }
        n1[grow] = s1;
        n2[grow] = s2;
    }

    {
        f32x4 acc[2][2]; zero_acc<2, 2>(acc);
        compute_tiles<2, 2, 256>(acc, bufA, ASTR, WTin3F, wv * 32, ln);
        store_tiles<2, 2>(acc, bufB, wv * 32, b_in3, 256, 1, ln);
    }
    __syncthreads();
    {
        f32x4 acc[2][2]; zero_acc<2, 2>(acc);
        compute_tiles<2, 2, 256>(acc, bufB, ASTR, WTconvF, wv * 32, ln);
        store_tiles<2, 2>(acc, bufA, wv * 32, nullptr, 256, 0, ln);
    }
    __syncthreads();

    int b = row0 >> 12;
    int c0 = (row0 & 4095) >> 5;
    unsigned short* dst = xwTb + (size_t)(b * 128 + c0) * (256 * 32);
#pragma unroll
    for (int p = 0; p < 2; ++p) {
        int idx = p * 512 + tid;
        int h = idx >> 2, g = idx & 3;
        unsigned int w[4];
#pragma unroll
        for (int j = 0; j < 4; ++j) {
            unsigned int lo = bufA[(g * 8 + 2 * j) * ASTR + h];
            unsigned int hi = bufA[(g * 8 + 2 * j + 1) * ASTR + h];
            w[j] = lo | (hi << 16);
        }
        *(uint4*)(dst + (size_t)h * 32 + g * 8) = make_uint4(w[0], w[1], w[2], w[3]);
    }
}

// ---------------------------------------------------------------------------
// FUSED adj_conv + post head: 512 blocks x 512 thr; block = 32 rows (b,iidx).
// Phase 1: R15 adjacency pipeline, epilogue -> xcs (LDS).
// Phase 2: id head + momentum head chain in-LDS, writes d_out directly.
// LDS 78.3 KB -> 2 blocks/CU; resident blocks drift out of phase, mixing
// adj (MFMA/VALU-heavy) with post (latency-heavy) on the same CU.
// ---------------------------------------------------------------------------
__global__ __launch_bounds__(512, 4) void adj_post(
    const unsigned short* __restrict__ c1b, const unsigned short* __restrict__ c2b,
    const float* __restrict__ n1, const float* __restrict__ n2,
    const unsigned short* __restrict__ xwTb, const float* __restrict__ bconv,
    const float* __restrict__ X,
    const unsigned short* __restrict__ WTid1F, const float* __restrict__ b_id1,
    const unsigned short* __restrict__ WTid2F, const float* __restrict__ b_id2,
    const unsigned short* __restrict__ WTid3F, const float* __restrict__ b_id3,
    const unsigned short* __restrict__ WTooF, const float* __restrict__ boo,
    const unsigned short* __restrict__ WTm1F, const float* __restrict__ b_m1,
    const unsigned short* __restrict__ WTm2F, const float* __restrict__ b_m2,
    const unsigned short* __restrict__ WTm3F, const float* __restrict__ b_m3,
    const unsigned short* __restrict__ WTomF, const float* __restrict__ b_om,
    float* __restrict__ out)
{
    __shared__ unsigned short wls[2][32][136];
    __shared__ unsigned short xcs[32 * ASTR];
    __shared__ unsigned short bufA[32 * ASTR];
    __shared__ unsigned short bufB[32 * ASTR];
    __shared__ float lgs[32 * 32];

    int tid = threadIdx.x, wv = tid >> 6, ln = tid & 63, quad = ln >> 4, l15 = ln & 15;
    int blk = blockIdx.x;
    int b = (blk >> 1) & 3;
    int iidx = ((blk >> 3) << 1) | (blk & 1);
    int i0 = iidx * 32;
    size_t base = (size_t)b * NSEQ;
    size_t grow0 = base + i0;                   // global row of tile row 0

    // zero pad cols 256..295 of xcs and bufB (no conflict with adj phase)
#pragma unroll
    for (int p = 0; p < 3; ++p) {
        int idx = p * 512 + tid;
        if (idx < 1280) {
            int row = idx / 40, c = 256 + idx - row * 40;
            xcs[row * ASTR + c] = 0;
            bufB[row * ASTR + c] = 0;
        }
    }

    // ================= Phase 1: adjacency conv =================
    bf16x8 c1f0 = *(const bf16x8*)(c1b + (base + i0 + l15) * 32 + quad * 8);
    bf16x8 c1f1 = *(const bf16x8*)(c1b + (base + i0 + 16 + l15) * 32 + quad * 8);
    float4 n1v0 = *(const float4*)(n1 + base + i0 + quad * 4);
    float4 n1v1 = *(const float4*)(n1 + base + i0 + 16 + quad * 4);

    const unsigned short* xwp0 = xwTb + (size_t)b * (128 * 256 * 32)
                               + ((size_t)(wv * 32 + l15) * 32 + quad * 8);
    const unsigned short* xwp1 = xwp0 + 8192;
    const unsigned short* xwp2 = xwp0 + 16384;
    const unsigned short* xwp3 = xwp0 + 24576;
    const unsigned short* c2p  = c2b + (base + wv * 16 + l15) * 32 + quad * 8;
    const float* n2p = n2 + base + wv * 16 + l15;

    f32x4 acc[2][2];
#pragma unroll
    for (int i = 0; i < 2; ++i)
#pragma unroll
        for (int j = 0; j < 2; ++j) acc[i][j] = (f32x4){0.f, 0.f, 0.f, 0.f};

    bf16x8 c2f = *(const bf16x8*)c2p;
    float nn2 = *n2p;
    c2p += 4096; n2p += 128;
    {
        f32x4 d0 = (f32x4){0.f, 0.f, 0.f, 0.f};
        f32x4 d1 = (f32x4){0.f, 0.f, 0.f, 0.f};
        d0 = __builtin_amdgcn_mfma_f32_16x16x32_bf16(c1f0, c2f, d0, 0, 0, 0);
        d1 = __builtin_amdgcn_mfma_f32_16x16x32_bf16(c1f1, c2f, d1, 0, 0, 0);
#pragma unroll
        for (int r = 0; r < 4; ++r) {
            float D0 = fmaf(-2.f, d0[r], n1v0[r] + nn2);
            float D1 = fmaf(-2.f, d1[r], n1v1[r] + nn2);
            float t0 = __builtin_amdgcn_sqrtf(fmaxf(D0, 1e-12f));
            float t1 = __builtin_amdgcn_sqrtf(fmaxf(D1, 1e-12f));
            wls[0][quad * 4 + r][wv * 16 + l15]      = t2bf(__expf(t0 * -4.f));
            wls[0][16 + quad * 4 + r][wv * 16 + l15] = t2bf(__expf(t1 * -4.f));
        }
    }
    c2f = *(const bf16x8*)c2p;
    nn2 = *n2p;
    c2p += 4096; n2p += 128;
    __syncthreads();

    for (int itr = 0; itr < 32; ++itr) {
        int p = itr & 1;
        bf16x8 bfc[4][2];
#pragma unroll
        for (int ht = 0; ht < 2; ++ht) {
            bfc[0][ht] = *(const bf16x8*)(xwp0 + ht * 512);
            bfc[1][ht] = *(const bf16x8*)(xwp1 + ht * 512);
            bfc[2][ht] = *(const bf16x8*)(xwp2 + ht * 512);
            bfc[3][ht] = *(const bf16x8*)(xwp3 + ht * 512);
        }
        xwp0 += 32768; xwp1 += 32768; xwp2 += 32768; xwp3 += 32768;

        if (itr < 31) {
            f32x4 d0 = (f32x4){0.f, 0.f, 0.f, 0.f};
            f32x4 d1 = (f32x4){0.f, 0.f, 0.f, 0.f};
            d0 = __builtin_amdgcn_mfma_f32_16x16x32_bf16(c1f0, c2f, d0, 0, 0, 0);
            d1 = __builtin_amdgcn_mfma_f32_16x16x32_bf16(c1f1, c2f, d1, 0, 0, 0);
            bf16x8 c2n; float nnn;
            if (itr < 30) {
                c2n = *(const bf16x8*)c2p;
                nnn = *n2p;
                c2p += 4096; n2p += 128;
            }
#pragma unroll
            for (int r = 0; r < 4; ++r) {
                float D0 = fmaf(-2.f, d0[r], n1v0[r] + nn2);
                float D1 = fmaf(-2.f, d1[r], n1v1[r] + nn2);
                float t0 = __builtin_amdgcn_sqrtf(fmaxf(D0, 1e-12f));
                float t1 = __builtin_amdgcn_sqrtf(fmaxf(D1, 1e-12f));
                wls[p ^ 1][quad * 4 + r][wv * 16 + l15]      = t2bf(__expf(t0 * -4.f));
                wls[p ^ 1][16 + quad * 4 + r][wv * 16 + l15] = t2bf(__expf(t1 * -4.f));
            }
            if (itr < 30) { c2f = c2n; nn2 = nnn; }
        }

#pragma unroll
        for (int ks = 0; ks < 4; ++ks) {
            bf16x8 af0 = *(const bf16x8*)&wls[p][l15][ks * 32 + quad * 8];
            bf16x8 af1 = *(const bf16x8*)&wls[p][16 + l15][ks * 32 + quad * 8];
            acc[0][0] = __builtin_amdgcn_mfma_f32_16x16x32_bf16(af0, bfc[ks][0], acc[0][0], 0, 0, 0);
            acc[0][1] = __builtin_amdgcn_mfma_f32_16x16x32_bf16(af0, bfc[ks][1], acc[0][1], 0, 0, 0);
            acc[1][0] = __builtin_amdgcn_mfma_f32_16x16x32_bf16(af1, bfc[ks][0], acc[1][0], 0, 0, 0);
            acc[1][1] = __builtin_amdgcn_mfma_f32_16x16x32_bf16(af1, bfc[ks][1], acc[1][1], 0, 0, 0);
        }
        __syncthreads();
    }

    // adj epilogue -> xcs (LDS), cols 0..255
#pragma unroll
    for (int mi = 0; mi < 2; ++mi) {
#pragma unroll
        for (int ht = 0; ht < 2; ++ht) {
            int h = wv * 32 + ht * 16 + l15;
            float bv = bconv[h];
#pragma unroll
            for (int r = 0; r < 4; ++r) {
                int lrow = mi * 16 + quad * 4 + r;
                xcs[lrow * ASTR + h] = f2bf(selu_f(acc[mi][ht][r] + bv));
            }
        }
    }
    __syncthreads();

    // ================= Phase 2: id + momentum heads =================
    {
        f32x4 a2[2][2]; zero_acc<2, 2>(a2);
        compute_tiles<2, 2, 256>(a2, xcs, ASTR, WTid1F, wv * 32, ln);
        store_tiles<2, 2>(a2, bufA, wv * 32, b_id1, 256, 1, ln);
    }
    __syncthreads();
    {
        f32x4 a2[2][2]; zero_acc<2, 2>(a2);
        compute_tiles<2, 2, 256>(a2, bufA, ASTR, WTid2F, wv * 32, ln);
        store_tiles<2, 2>(a2, bufB, wv * 32, b_id2, 256, 1, ln);
    }
    __syncthreads();
    {
        f32x4 a2[2][2]; zero_acc<2, 2>(a2);
        compute_tiles<2, 2, 256>(a2, bufB, ASTR, WTid3F, wv * 32, ln);
        store_tiles<2, 2>(a2, bufA, wv * 32, b_id3, 256, 1, ln);
    }
    __syncthreads();
    if (wv == 0) {
        f32x4 a2[2][2]; zero_acc<2, 2>(a2);
        compute_tiles<2, 2, 256>(a2, bufA, ASTR, WTooF, 0, ln);
#pragma unroll
        for (int nt = 0; nt < 2; ++nt) {
            int col = nt * 16 + l15;
            float bv = boo[col];
#pragma unroll
            for (int i = 0; i < 2; ++i)
#pragma unroll
                for (int r = 0; r < 4; ++r)
                    lgs[(i * 16 + quad * 4 + r) * 32 + col] = a2[i][nt][r] + bv;
        }
    }
    __syncthreads();
    if (tid < 32) {
        float* op = out + (grow0 + tid) * 13;
#pragma unroll
        for (int c = 0; c < 8; ++c) {
            float lg = lgs[tid * 32 + c];
            op[c] = lg;
            xcs[tid * ASTR + 256 + c] = f2bf(selu_f(lg));
        }
        op[11] = lgs[tid * 32 + 16];
        op[12] = lgs[tid * 32 + 17];
    }
    __syncthreads();
    {
        f32x4 a2[2][2]; zero_acc<2, 2>(a2);
        compute_tiles<2, 2, 288>(a2, xcs, ASTR, WTm1F, wv * 32, ln);
        store_tiles<2, 2>(a2, bufB, wv * 32, b_m1, 264, 1, ln);
        if (wv == 1) {
            f32x4 acx[2][1]; zero_acc<2, 1>(acx);
            compute_tiles<2, 1, 288>(acx, xcs, ASTR, WTm1F, 256, ln);
            store_tiles<2, 1>(acx, bufB, 256, b_m1, 264, 1, ln);
        }
    }
    __syncthreads();
    {
        f32x4 a2[2][2]; zero_acc<2, 2>(a2);
        compute_tiles<2, 2, 288>(a2, bufB, ASTR, WTm2F, wv * 32, ln);
        store_tiles<2, 2>(a2, bufA, wv * 32, b_m2, 256, 1, ln);
    }
    __syncthreads();
    {
        f32x4 a2[2][2]; zero_acc<2, 2>(a2);
        compute_tiles<2, 2, 256>(a2, bufA, ASTR, WTm3F, wv * 32, ln);
        store_tiles<2, 2>(a2, bufB, wv * 32, b_m3, 256, 1, ln);
    }
    __syncthreads();
    if (wv == 0) {
        f32x4 a2[2][1]; zero_acc<2, 1>(a2);
        compute_tiles<2, 1, 256>(a2, bufB, ASTR, WTomF, 0, ln);
        if (l15 < 3) {
            float bv = b_om[l15];
#pragma unroll
            for (int i = 0; i < 2; ++i)
#pragma unroll
                for (int r = 0; r < 4; ++r) {
                    size_t grow = grow0 + i * 16 + quad * 4 + r;
                    out[grow * 13 + 8 + l15] =
                        X[grow * 15 + 2 + l15] + a2[i][0][r] + bv;
                }
        }
    }
}

extern "C" void kernel_launch(void* const* d_in, const int* in_sizes, int n_in,
                              void* d_out, int out_size, void* d_ws, size_t ws_size,
                              hipStream_t stream) {
    (void)in_sizes; (void)n_in; (void)out_size; (void)ws_size;

    const float* X = (const float*)d_in[0];
    const float* W_dc1 = (const float*)d_in[1];  const float* b_dc1 = (const float*)d_in[2];
    const float* W_dc21 = (const float*)d_in[3]; const float* b_dc21 = (const float*)d_in[4];
    const float* W_dc22 = (const float*)d_in[5]; const float* b_dc22 = (const float*)d_in[6];
    const float* W_in1 = (const float*)d_in[7];  const float* b_in1 = (const float*)d_in[8];
    const float* W_in2 = (const float*)d_in[9];  const float* b_in2 = (const float*)d_in[10];
    const float* W_in3 = (const float*)d_in[11]; const float* b_in3 = (const float*)d_in[12];
    const float* W_conv = (const float*)d_in[13]; const float* b_conv = (const float*)d_in[14];
    const float* W_id1 = (const float*)d_in[15]; const float* b_id1 = (const float*)d_in[16];
    const float* W_id2 = (const float*)d_in[17]; const float* b_id2 = (const float*)d_in[18];
    const float* W_id3 = (const float*)d_in[19]; const float* b_id3 = (const float*)d_in[20];
    const float* W_oid = (const float*)d_in[21]; const float* b_oid = (const float*)d_in[22];
    const float* W_och = (const float*)d_in[23]; const float* b_och = (const float*)d_in[24];
    const float* W_m1 = (const float*)d_in[25];  const float* b_m1 = (const float*)d_in[26];
    const float* W_m2 = (const float*)d_in[27];  const float* b_m2 = (const float*)d_in[28];
    const float* W_m3 = (const float*)d_in[29];  const float* b_m3 = (const float*)d_in[30];
    const float* W_om = (const float*)d_in[31];  const float* b_om = (const float*)d_in[32];

    const size_t M = MROWS;
    char* pw = (char*)d_ws;
    auto alloc = [&](size_t bytes) -> void* {
        void* r = (void*)pw;
        pw += (bytes + 255) & ~(size_t)255;
        return r;
    };
    unsigned short* c1b = (unsigned short*)alloc(M * 32 * 2);
    unsigned short* c2b = (unsigned short*)alloc(M * 32 * 2);
    float* n1 = (float*)alloc(M * 4);
    float* n2 = (float*)alloc(M * 4);
    unsigned short* xwTb = (unsigned short*)alloc((size_t)4 * 128 * 256 * 32 * 2);
    unsigned short* WTdF   = (unsigned short*)alloc((size_t)2 * 16 * 1 * 512 * 2);
    unsigned short* WTc12F = (unsigned short*)alloc((size_t)4 * 8 * 512 * 2);
    unsigned short* WTin2F = (unsigned short*)alloc((size_t)16 * 8 * 512 * 2);
    unsigned short* WTin3F = (unsigned short*)alloc((size_t)16 * 8 * 512 * 2);
    unsigned short* WTconvF = (unsigned short*)alloc((size_t)16 * 8 * 512 * 2);
    unsigned short* WTid1F = (unsigned short*)alloc((size_t)16 * 8 * 512 * 2);
    unsigned short* WTid2F = (unsigned short*)alloc((size_t)16 * 8 * 512 * 2);
    unsigned short* WTid3F = (unsigned short*)alloc((size_t)16 * 8 * 512 * 2);
    unsigned short* WTm3F  = (unsigned short*)alloc((size_t)16 * 8 * 512 * 2);
    unsigned short* WTooF  = (unsigned short*)alloc((size_t)2 * 8 * 512 * 2);
    unsigned short* WTm1F  = (unsigned short*)alloc((size_t)17 * 9 * 512 * 2);
    unsigned short* WTm2F  = (unsigned short*)alloc((size_t)16 * 9 * 512 * 2);
    unsigned short* WTomF  = (unsigned short*)alloc((size_t)1 * 8 * 512 * 2);
    float* bc12 = (float*)alloc(64 * 4);
    float* boo = (float*)alloc(32 * 4);
    float* bcat = (float*)alloc(512 * 4);

    PrepArgs pa;
    int off = 0;
    auto ent = [&](const float* W, unsigned short* WTf, int N, int K, int ntiles) {
        PrepEnt e; e.W = W; e.WTf = WTf; e.N = N; e.K = K; e.ntiles = ntiles;
        e.KS = (K + 31) / 32;
        e.tilesN = (ntiles * 16 + 31) / 32;
        e.tileOff = off;
        off += e.tilesN * e.KS;
        return e;
    };
    pa.e[0]  = ent(W_dc1,  WTdF,                256, 25,  16);
    pa.e[1]  = ent(W_in1,  WTdF + 16 * 512,     256, 25,  16);
    pa.e[2]  = ent(W_dc21, WTc12F,              32,  256, 2);
    pa.e[3]  = ent(W_dc22, WTc12F + 2 * 8 * 512, 32, 256, 2);
    pa.e[4]  = ent(W_in2,  WTin2F,              256, 256, 16);
    pa.e[5]  = ent(W_in3,  WTin3F,              256, 256, 16);
    pa.e[6]  = ent(W_conv, WTconvF,             256, 256, 16);
    pa.e[7]  = ent(W_id1,  WTid1F,              256, 256, 16);
    pa.e[8]  = ent(W_id2,  WTid2F,              256, 256, 16);
    pa.e[9]  = ent(W_id3,  WTid3F,              256, 256, 16);
    pa.e[10] = ent(W_m3,   WTm3F,               256, 256, 16);
    pa.e[11] = ent(W_oid,  WTooF,               8,   256, 1);
    pa.e[12] = ent(W_och,  WTooF + 8 * 512,     2,   256, 1);
    pa.e[13] = ent(W_m1,   WTm1F,               264, 264, 17);
    pa.e[14] = ent(W_m2,   WTm2F,               256, 264, 16);
    pa.e[15] = ent(W_om,   WTomF,               3,   256, 1);
    pa.b21 = b_dc21; pa.b22 = b_dc22; pa.boid = b_oid; pa.boch = b_och;
    pa.bdc1 = b_dc1; pa.bin1 = b_in1;
    pa.bc12 = bc12; pa.boo = boo; pa.bcat = bcat;
    prep_kernel<<<dim3(off, 2), 256, 0, stream>>>(pa);

    pre_mega<<<dim3(512), 512, 0, stream>>>(X, WTdF, bcat, WTc12F, bc12,
                                            WTin2F, b_in2, WTin3F, b_in3, WTconvF,
                                            c1b, c2b, n1, n2, xwTb);

    adj_post<<<dim3(512), 512, 0, stream>>>(c1b, c2b, n1, n2, xwTb, b_conv, X,
                                            WTid1F, b_id1, WTid2F, b_id2, WTid3F, b_id3,
                                            WTooF, boo, WTm1F, b_m1, WTm2F, b_m2,
                                            WTm3F, b_m3, WTomF, b_om, (float*)d_out);
}